// Round 2
// baseline (702.276 us; speedup 1.0000x reference)
//
#include <hip/hip_runtime.h>

// ---------------- CSR build ----------------
// NOTE: harness delivers integer inputs as int32 (reference int64 is narrowed).

__global__ void k_count(const int* __restrict__ dst, int E, int* __restrict__ deg) {
  int i = blockIdx.x * blockDim.x + threadIdx.x;
  int stride = gridDim.x * blockDim.x;
  for (; i < E; i += stride) {
    atomicAdd(&deg[dst[i]], 1);
  }
}

// Per-wave prefix sum of counts + one global-cursor atomic per wave allocates
// each node's CSR slice (slice order across nodes is irrelevant).
__global__ void k_alloc(const int* __restrict__ deg, int N, float* __restrict__ dinv,
                        int* __restrict__ row_start, int* __restrict__ cursor) {
  int i = blockIdx.x * blockDim.x + threadIdx.x;
  int lane = threadIdx.x & 63;
  int cnt = (i < N) ? deg[i] : 0;
  int v = cnt;
#pragma unroll
  for (int off = 1; off < 64; off <<= 1) {
    int u = __shfl_up(v, off);
    if (lane >= off) v += u;
  }
  int total = __shfl(v, 63);
  int base = 0;
  if (lane == 0) base = atomicAdd(cursor, total);
  base = __shfl(base, 0);
  if (i < N) {
    row_start[i] = base + v - cnt;           // exclusive prefix within wave
    dinv[i] = rsqrtf((float)(cnt + 1));      // +1 for the self-loop
  }
}

__global__ void k_scatter(const int* __restrict__ src, const int* __restrict__ dst,
                          int E, const int* __restrict__ row_start, int* __restrict__ fill,
                          int* __restrict__ col) {
  int i = blockIdx.x * blockDim.x + threadIdx.x;
  int stride = gridDim.x * blockDim.x;
  for (; i < E; i += stride) {
    int s = src[i], d = dst[i];
    int p = row_start[d] + atomicAdd(&fill[d], 1);
    col[p] = s;
  }
}

// ---------------- GEMM: G[row,col] = dinv[row] * sum_k X[row,k] * W[k,col] ----------------
// col = threadIdx.x; W column cached in VGPRs; x-row address is wave-uniform
// (derived only from blockIdx + loop) so the compiler can use scalar loads.

template <int K, int NC, int BS>
__global__ __launch_bounds__(BS) void k_gemm(const float* __restrict__ X,
                                             const float* __restrict__ W,
                                             const float* __restrict__ dinv,
                                             float* __restrict__ G, int N) {
  int col = threadIdx.x;
  bool active = (col < NC);
  float w[K];
#pragma unroll
  for (int k = 0; k < K; ++k) w[k] = active ? W[k * NC + col] : 0.f;

  for (int row = blockIdx.x; row < N; row += gridDim.x) {
    const float4* xr = (const float4*)(X + (size_t)row * K);
    float a0 = 0.f, a1 = 0.f, a2 = 0.f, a3 = 0.f;
#pragma unroll
    for (int k4 = 0; k4 < K / 4; ++k4) {
      float4 xv = xr[k4];
      a0 = fmaf(xv.x, w[4 * k4 + 0], a0);
      a1 = fmaf(xv.y, w[4 * k4 + 1], a1);
      a2 = fmaf(xv.z, w[4 * k4 + 2], a2);
      a3 = fmaf(xv.w, w[4 * k4 + 3], a3);
    }
    if (active) G[(size_t)row * NC + col] = ((a0 + a1) + (a2 + a3)) * dinv[row];
  }
}

// ---------------- Aggregation 1: h2 = relu(dinv[n]*(g1[n] + sum g1[nbr]) + b1), F=128 ----------------
// One wave per node, float2 per lane (64*8B = 512B row).

__global__ void k_agg1(const float* __restrict__ g1, const int* __restrict__ row_start,
                       const int* __restrict__ deg, const int* __restrict__ col,
                       const float* __restrict__ dinv, const float* __restrict__ b1,
                       float* __restrict__ h2, int N) {
  int node = blockIdx.x * 4 + (threadIdx.x >> 6);
  if (node >= N) return;
  int lane = threadIdx.x & 63;
  const float2* gb = (const float2*)g1;
  float2 acc = gb[(size_t)node * 64 + lane];  // self-loop term (g1 already has dinv[s])
  int start = row_start[node], cnt = deg[node];
  int j = 0;
  for (; j + 4 <= cnt; j += 4) {
    int s0 = col[start + j + 0], s1 = col[start + j + 1];
    int s2 = col[start + j + 2], s3 = col[start + j + 3];
    float2 v0 = gb[(size_t)s0 * 64 + lane];
    float2 v1 = gb[(size_t)s1 * 64 + lane];
    float2 v2 = gb[(size_t)s2 * 64 + lane];
    float2 v3 = gb[(size_t)s3 * 64 + lane];
    acc.x += (v0.x + v1.x) + (v2.x + v3.x);
    acc.y += (v0.y + v1.y) + (v2.y + v3.y);
  }
  for (; j < cnt; ++j) {
    int s = col[start + j];
    float2 v = gb[(size_t)s * 64 + lane];
    acc.x += v.x;
    acc.y += v.y;
  }
  float dn = dinv[node];
  float2 bb = ((const float2*)b1)[lane];
  float2 o;
  o.x = fmaxf(fmaf(acc.x, dn, bb.x), 0.f);
  o.y = fmaxf(fmaf(acc.y, dn, bb.y), 0.f);
  ((float2*)h2)[(size_t)node * 64 + lane] = o;
}

// ---------------- Aggregation 2: out = dinv[n]*(g2[n] + sum g2[nbr]) + b2, C=40 ----------------

__global__ void k_agg2(const float* __restrict__ g2, const int* __restrict__ row_start,
                       const int* __restrict__ deg, const int* __restrict__ col,
                       const float* __restrict__ dinv, const float* __restrict__ b2,
                       float* __restrict__ out, int N, int C) {
  int node = blockIdx.x * 4 + (threadIdx.x >> 6);
  if (node >= N) return;
  int lane = threadIdx.x & 63;
  if (lane >= C) return;
  float acc = g2[(size_t)node * C + lane];  // self-loop term
  int start = row_start[node], cnt = deg[node];
  int j = 0;
  for (; j + 4 <= cnt; j += 4) {
    int s0 = col[start + j + 0], s1 = col[start + j + 1];
    int s2 = col[start + j + 2], s3 = col[start + j + 3];
    float v0 = g2[(size_t)s0 * C + lane];
    float v1 = g2[(size_t)s1 * C + lane];
    float v2 = g2[(size_t)s2 * C + lane];
    float v3 = g2[(size_t)s3 * C + lane];
    acc += (v0 + v1) + (v2 + v3);
  }
  for (; j < cnt; ++j) acc += g2[(size_t)col[start + j] * C + lane];
  out[(size_t)node * C + lane] = fmaf(acc, dinv[node], b2[lane]);
}

// ---------------- launch ----------------

extern "C" void kernel_launch(void* const* d_in, const int* in_sizes, int n_in,
                              void* d_out, int out_size, void* d_ws, size_t ws_size,
                              hipStream_t stream) {
  const float* x = (const float*)d_in[0];
  const int* ei = (const int*)d_in[1];   // int64 in reference -> int32 on device
  const float* W1 = (const float*)d_in[2];
  const float* b1 = (const float*)d_in[3];
  const float* W2 = (const float*)d_in[4];
  const float* b2 = (const float*)d_in[5];

  const int F = in_sizes[3];       // 128 (hidden == num_features here)
  const int C = in_sizes[5];       // 40
  const int N = in_sizes[0] / F;   // 100000
  const int E = in_sizes[1] / 2;   // 1600000
  const int* esrc = ei;
  const int* edst = ei + E;

  // workspace layout (bytes), all offsets 256-aligned:
  //   deg:       0        .. 400384   (int[N])
  //   fill:      400384   .. 800768   (int[N])
  //   cursor:    800768   .. 801792   (int)
  //   dinv:      801792   .. 1202176  (float[N])
  //   row_start: 1202176  .. 1602560  (int[N])
  //   col:       1602560  .. 8002560  (int[E])
  //   g1/g2:     8002560  .. 59202560 (float[N*128]; g2 reuses after agg1)
  //   h2:        59202560 .. 110402560(float[N*128])
  char* ws = (char*)d_ws;
  int* deg = (int*)(ws + 0);
  int* fill = (int*)(ws + 400384);
  int* cursor = (int*)(ws + 800768);
  float* dinv = (float*)(ws + 801792);
  int* row_start = (int*)(ws + 1202176);
  int* colx = (int*)(ws + 1602560);
  float* g1 = (float*)(ws + 8002560);
  float* h2 = (float*)(ws + 59202560);
  float* g2 = g1;  // g1 is dead after k_agg1

  hipMemsetAsync(d_ws, 0, 801792, stream);  // zero deg, fill, cursor

  k_count<<<2048, 256, 0, stream>>>(edst, E, deg);
  k_alloc<<<(N + 255) / 256, 256, 0, stream>>>(deg, N, dinv, row_start, cursor);
  k_scatter<<<2048, 256, 0, stream>>>(esrc, edst, E, row_start, fill, colx);

  k_gemm<128, 128, 128><<<1536, 128, 0, stream>>>(x, W1, dinv, g1, N);
  k_agg1<<<(N + 3) / 4, 256, 0, stream>>>(g1, row_start, deg, colx, dinv, b1, h2, N);
  k_gemm<128, 40, 64><<<3072, 64, 0, stream>>>(h2, W2, dinv, g2, N);
  k_agg2<<<(N + 3) / 4, 256, 0, stream>>>(g2, row_start, deg, colx, dinv, b2,
                                          (float*)d_out, N, C);
}